// Round 1
// baseline (341.907 us; speedup 1.0000x reference)
//
#include <hip/hip_runtime.h>

// CORDIV stochastic-computing divider.
// Per lane n: sr[4] shift register in registers; 16 sequential steps:
//   r   = rng_table[t % 4]           (wave-uniform)
//   q   = (divisor[t][n] == 1) ? dividend[t][n] : sr[r]
//   out[t][n] = q;  sr = {q, sr[0], sr[1], sr[2]}
// Memory-bound: 288 MiB read + 128 MiB write -> ~70us roofline at 6.3 TB/s.
// float4 vectorization: one thread handles 4 adjacent lanes; all global
// accesses coalesced (consecutive threads -> consecutive 16B at each t).

#define SC_T 16
#define SC_BUF 4

__global__ __launch_bounds__(256) void cordiv_kernel(
    const float4* __restrict__ dividend,
    const float4* __restrict__ divisor,
    const float4* __restrict__ sr_init,
    const int*    __restrict__ rng_table,
    float4*       __restrict__ out,
    int n4)   // N / 4
{
    int gid = blockIdx.x * blockDim.x + threadIdx.x;
    if (gid >= n4) return;

    // rng table: uniform address -> scalar loads; values are uniform per t.
    const int r0 = rng_table[0];
    const int r1 = rng_table[1];
    const int r2 = rng_table[2];
    const int r3 = rng_table[3];
    const int rtab[SC_BUF] = {r0, r1, r2, r3};

    float4 sr0 = sr_init[0 * n4 + gid];
    float4 sr1 = sr_init[1 * n4 + gid];
    float4 sr2 = sr_init[2 * n4 + gid];
    float4 sr3 = sr_init[3 * n4 + gid];

#pragma unroll
    for (int t = 0; t < SC_T; ++t) {
        const int r = rtab[t & (SC_BUF - 1)];   // constant-folds per unrolled t
        const float4 dvd = dividend[t * n4 + gid];
        const float4 dvs = divisor[t * n4 + gid];

        // historic quotient: uniform select of sr[r]
        const float4 hq = (r == 0) ? sr0 : (r == 1) ? sr1 : (r == 2) ? sr2 : sr3;

        float4 q;
        q.x = (dvs.x == 1.0f) ? dvd.x : hq.x;
        q.y = (dvs.y == 1.0f) ? dvd.y : hq.y;
        q.z = (dvs.z == 1.0f) ? dvd.z : hq.z;
        q.w = (dvs.w == 1.0f) ? dvd.w : hq.w;

        out[t * n4 + gid] = q;

        // shift register push (register renaming after full unroll)
        sr3 = sr2; sr2 = sr1; sr1 = sr0; sr0 = q;
    }
}

extern "C" void kernel_launch(void* const* d_in, const int* in_sizes, int n_in,
                              void* d_out, int out_size, void* d_ws, size_t ws_size,
                              hipStream_t stream) {
    const float* dividend = (const float*)d_in[0];   // [T, N]
    const float* divisor  = (const float*)d_in[1];   // [T, N]
    const float* sr_init  = (const float*)d_in[2];   // [BUF_DEP, N]
    const int*   rng      = (const int*)d_in[3];     // [4]
    float*       out      = (float*)d_out;           // [T, N]

    const int n  = in_sizes[0] / SC_T;   // N
    const int n4 = n / 4;                // N divisible by 4 (N = 2^21)

    const int block = 256;
    const int grid  = (n4 + block - 1) / block;

    cordiv_kernel<<<grid, block, 0, stream>>>(
        (const float4*)dividend, (const float4*)divisor,
        (const float4*)sr_init, rng, (float4*)out, n4);
}